// Round 1
// baseline (270.597 us; speedup 1.0000x reference)
//
#include <hip/hip_runtime.h>

typedef __bf16 bf16_t;
typedef __bf16 bf16x8 __attribute__((ext_vector_type(8)));
typedef __bf16 bf16x4 __attribute__((ext_vector_type(4)));
typedef float f32x4 __attribute__((ext_vector_type(4)));

#define MFMA_BF16(a, b, c) __builtin_amdgcn_mfma_f32_16x16x32_bf16((a), (b), (c), 0, 0, 0)

__device__ __forceinline__ void gload16(const bf16_t* g, bf16_t* l) {
  __builtin_amdgcn_global_load_lds(
      (__attribute__((address_space(1))) void*)(g),
      (__attribute__((address_space(3))) void*)(l), 16, 0, 0);
}

// ---------------------------------------------------------------------------
// Cast x and the 4 weights f32 -> bf16.  wbf layout: [Wq | Wk | Wv | Wo]
// ---------------------------------------------------------------------------
__global__ void cast_all(const float* __restrict__ x, const float* __restrict__ wk,
                         const float* __restrict__ wq, const float* __restrict__ wv,
                         const float* __restrict__ wo, bf16_t* __restrict__ xbf,
                         bf16_t* __restrict__ wbf) {
  const size_t NX = 4194304, NW = 1048576;
  size_t i = (size_t)blockIdx.x * blockDim.x + threadIdx.x;
  const size_t total4 = (NX + 4 * NW) / 4;
  const size_t stride = (size_t)gridDim.x * blockDim.x;
  for (; i < total4; i += stride) {
    size_t f = i * 4;
    const float* src;
    bf16_t* dst;
    if (f < NX) {
      src = x + f;
      dst = xbf + f;
    } else {
      size_t g = f - NX;
      size_t wsel = g >> 20;
      size_t off = g & (NW - 1);
      dst = wbf + g;
      src = (wsel == 0) ? wq + off : (wsel == 1) ? wk + off : (wsel == 2) ? wv + off : wo + off;
    }
    float4 v = *(const float4*)src;
    bf16x4 o;
    o[0] = (bf16_t)v.x; o[1] = (bf16_t)v.y; o[2] = (bf16_t)v.z; o[3] = (bf16_t)v.w;
    *(bf16x4*)dst = o;
  }
}

// ---------------------------------------------------------------------------
// NT GEMM: C[m][n] = sum_k A[m][k] * W[n][k].  128x128 tile, BK=32, 4 waves.
// W sections of 1024 cols selected by blockIdx.y / blocksPerSect (for fused QKV).
// ---------------------------------------------------------------------------
template <typename TOUT>
__global__ __launch_bounds__(256) void gemm_nt(const bf16_t* __restrict__ A,
                                               const bf16_t* __restrict__ W,
                                               TOUT* __restrict__ C, int K, int ldc,
                                               int blocksPerSect) {
  __shared__ bf16_t As[128 * 32];
  __shared__ bf16_t Bs[128 * 32];
  const int t = threadIdx.x;
  const int l = t & 63, w = t >> 6;
  const int wm = w >> 1, wn = w & 1;
  const int lr = l & 15, lg = l >> 4;
  const int bm = blockIdx.x;
  const int by = blockIdx.y;
  const int sect = by / blocksPerSect;
  const int bn = by - sect * blocksPerSect;
  const bf16_t* Wp = W + ((size_t)sect << 20);
  const int n0 = sect * 1024 + bn * 128;

  const bf16_t* ag = A + (size_t)(bm * 128 + (t >> 2)) * K + (t & 3) * 8;
  const bf16_t* bg = Wp + (size_t)(bn * 128 + (t >> 2)) * K + (t & 3) * 8;
  const size_t rs64 = (size_t)64 * K;

  f32x4 acc[4][4];
#pragma unroll
  for (int i = 0; i < 4; ++i)
#pragma unroll
    for (int j = 0; j < 4; ++j) acc[i][j] = (f32x4){0.f, 0.f, 0.f, 0.f};

  for (int k0 = 0; k0 < K; k0 += 32) {
    __syncthreads();
    gload16(ag, As + t * 8);
    gload16(ag + rs64, As + 2048 + t * 8);
    gload16(bg, Bs + t * 8);
    gload16(bg + rs64, Bs + 2048 + t * 8);
    ag += 32;
    bg += 32;
    __syncthreads();
    bf16x8 af[4], bfr[4];
#pragma unroll
    for (int mf = 0; mf < 4; ++mf)
      af[mf] = *(const bf16x8*)(As + (wm * 64 + mf * 16 + lr) * 32 + lg * 8);
#pragma unroll
    for (int nf = 0; nf < 4; ++nf)
      bfr[nf] = *(const bf16x8*)(Bs + (wn * 64 + nf * 16 + lr) * 32 + lg * 8);
#pragma unroll
    for (int mf = 0; mf < 4; ++mf)
#pragma unroll
      for (int nf = 0; nf < 4; ++nf)
        acc[mf][nf] = MFMA_BF16(af[mf], bfr[nf], acc[mf][nf]);
  }

#pragma unroll
  for (int mf = 0; mf < 4; ++mf)
#pragma unroll
    for (int nf = 0; nf < 4; ++nf)
#pragma unroll
      for (int j = 0; j < 4; ++j) {
        int row = bm * 128 + wm * 64 + mf * 16 + lg * 4 + j;
        int col = n0 + wn * 64 + nf * 16 + lr;
        C[(size_t)row * ldc + col] = (TOUT)acc[mf][nf][j];
      }
}

// ---------------------------------------------------------------------------
// Flash attention (causal).  Block = 4 waves = 64 q rows of one (b,h).
// qkv: [4096][3072] bf16, sections Q|K|V of 1024 cols.  out: [4096][1024] bf16.
// ---------------------------------------------------------------------------
__global__ __launch_bounds__(256) void attn_fwd(const bf16_t* __restrict__ qkv,
                                                bf16_t* __restrict__ out) {
  __shared__ bf16_t Ks[64 * 64];
  __shared__ bf16_t Vts[64 * 64];
  __shared__ bf16_t Ps[4][16 * 64];
  const int t = threadIdx.x, l = t & 63, w = t >> 6;
  const int lr = l & 15, lg = l >> 4;
  const int qt = blockIdx.x;
  const int bh = blockIdx.y;
  const int b = bh >> 4, h = bh & 15;
  const size_t rowStr = 3072;

  const bf16_t* Qg = qkv + (size_t)(b * 2048 + qt * 64 + w * 16 + lr) * rowStr + h * 64 + lg * 8;
  bf16x8 qf0 = *(const bf16x8*)(Qg);
  bf16x8 qf1 = *(const bf16x8*)(Qg + 32);

  f32x4 acc_o[4];
#pragma unroll
  for (int nf = 0; nf < 4; ++nf) acc_o[nf] = (f32x4){0.f, 0.f, 0.f, 0.f};
  float m_r[4] = {-1e30f, -1e30f, -1e30f, -1e30f};
  float l_r[4] = {0.f, 0.f, 0.f, 0.f};

  bf16_t* Pw = &Ps[w][0];

  for (int kt = 0; kt <= qt; ++kt) {
    __syncthreads();
    // --- stage K (linear, global_load_lds) and V^T (reg-staged transpose) ---
#pragma unroll
    for (int r = 0; r < 2; ++r) {
      int row = r * 32 + (t >> 3);
      int c0 = (t & 7) * 8;
      const bf16_t* srcK = qkv + (size_t)(b * 2048 + kt * 64 + row) * rowStr + 1024 + h * 64 + c0;
      gload16(srcK, Ks + r * 2048 + t * 8);
    }
#pragma unroll
    for (int r = 0; r < 2; ++r) {
      int row = r * 32 + (t >> 3);
      int c0 = (t & 7) * 8;
      const bf16_t* srcV = qkv + (size_t)(b * 2048 + kt * 64 + row) * rowStr + 2048 + h * 64 + c0;
      bf16x8 v = *(const bf16x8*)srcV;
#pragma unroll
      for (int j = 0; j < 8; ++j) Vts[(c0 + j) * 64 + row] = v[j];
    }
    __syncthreads();

    // --- S = Q K^T / 8 ---
    f32x4 sc[4];
#pragma unroll
    for (int nf = 0; nf < 4; ++nf) sc[nf] = (f32x4){0.f, 0.f, 0.f, 0.f};
#pragma unroll
    for (int nf = 0; nf < 4; ++nf) {
      const bf16_t* kp = Ks + (nf * 16 + lr) * 64 + lg * 8;
      bf16x8 b0 = *(const bf16x8*)kp;
      bf16x8 b1 = *(const bf16x8*)(kp + 32);
      sc[nf] = MFMA_BF16(qf0, b0, sc[nf]);
      sc[nf] = MFMA_BF16(qf1, b1, sc[nf]);
    }
    float s[4][4];
    const bool diag = (kt == qt);
#pragma unroll
    for (int nf = 0; nf < 4; ++nf)
#pragma unroll
      for (int j = 0; j < 4; ++j) {
        float v = sc[nf][j] * 0.125f;
        if (diag) {
          int col = nf * 16 + lr;
          int row = w * 16 + lg * 4 + j;
          if (col > row) v = -1e30f;
        }
        s[nf][j] = v;
      }

    // --- online softmax, P -> per-wave LDS (bf16, A-operand layout) ---
#pragma unroll
    for (int j = 0; j < 4; ++j) {
      float rm = fmaxf(fmaxf(s[0][j], s[1][j]), fmaxf(s[2][j], s[3][j]));
      rm = fmaxf(rm, __shfl_xor(rm, 1, 16));
      rm = fmaxf(rm, __shfl_xor(rm, 2, 16));
      rm = fmaxf(rm, __shfl_xor(rm, 4, 16));
      rm = fmaxf(rm, __shfl_xor(rm, 8, 16));
      float mnew = fmaxf(m_r[j], rm);
      float sf = __expf(m_r[j] - mnew);
      m_r[j] = mnew;
      float ps = 0.f;
      float pj[4];
#pragma unroll
      for (int nf = 0; nf < 4; ++nf) {
        pj[nf] = __expf(s[nf][j] - mnew);
        ps += pj[nf];
      }
      ps += __shfl_xor(ps, 1, 16);
      ps += __shfl_xor(ps, 2, 16);
      ps += __shfl_xor(ps, 4, 16);
      ps += __shfl_xor(ps, 8, 16);
      l_r[j] = l_r[j] * sf + ps;
#pragma unroll
      for (int nf = 0; nf < 4; ++nf) acc_o[nf][j] *= sf;
#pragma unroll
      for (int nf = 0; nf < 4; ++nf) Pw[(lg * 4 + j) * 64 + nf * 16 + lr] = (bf16_t)pj[nf];
    }

    // --- O += P V ---
    bf16x8 ap0 = *(const bf16x8*)(Pw + lr * 64 + lg * 8);
    bf16x8 ap1 = *(const bf16x8*)(Pw + lr * 64 + 32 + lg * 8);
#pragma unroll
    for (int nf = 0; nf < 4; ++nf) {
      const bf16_t* vp = Vts + (nf * 16 + lr) * 64 + lg * 8;
      bf16x8 v0 = *(const bf16x8*)vp;
      bf16x8 v1 = *(const bf16x8*)(vp + 32);
      acc_o[nf] = MFMA_BF16(ap0, v0, acc_o[nf]);
      acc_o[nf] = MFMA_BF16(ap1, v1, acc_o[nf]);
    }
  }

  // --- normalize + write ---
#pragma unroll
  for (int nf = 0; nf < 4; ++nf)
#pragma unroll
    for (int j = 0; j < 4; ++j) {
      int row = qt * 64 + w * 16 + lg * 4 + j;
      int col = h * 64 + nf * 16 + lr;
      out[(size_t)(b * 2048 + row) * 1024 + col] = (bf16_t)(acc_o[nf][j] / l_r[j]);
    }
}

// ---------------------------------------------------------------------------
extern "C" void kernel_launch(void* const* d_in, const int* in_sizes, int n_in,
                              void* d_out, int out_size, void* d_ws, size_t ws_size,
                              hipStream_t stream) {
  const float* x = (const float*)d_in[0];
  const float* wk = (const float*)d_in[1];
  const float* wq = (const float*)d_in[2];
  const float* wv = (const float*)d_in[3];
  const float* wo = (const float*)d_in[4];

  bf16_t* xbf = (bf16_t*)d_ws;           // 4 Mi elems (8 MB)
  bf16_t* wbf = xbf + 4194304;           // 4 Mi elems (8 MB): [Wq|Wk|Wv|Wo]
  bf16_t* qkvbf = wbf + 4194304;         // 12 Mi elems (24 MB): [Q|K|V] cols
  bf16_t* attnbf = xbf;                  // alias: xbf dead after QKV gemm
  float* out = (float*)d_out;

  cast_all<<<dim3(2048), dim3(256), 0, stream>>>(x, wk, wq, wv, wo, xbf, wbf);
  gemm_nt<bf16_t><<<dim3(32, 24), dim3(256), 0, stream>>>(xbf, wbf, qkvbf, 1024, 3072, 8);
  attn_fwd<<<dim3(32, 32), dim3(256), 0, stream>>>(qkvbf, attnbf);
  gemm_nt<float><<<dim3(32, 8), dim3(256), 0, stream>>>(attnbf, wbf + 3 * 1048576, out, 1024,
                                                        1024, 8);
}

// Round 2
// 120.082 us; speedup vs baseline: 2.2534x; 2.2534x over previous
//
#include <hip/hip_runtime.h>

typedef __bf16 bf16_t;
typedef __bf16 bf16x8 __attribute__((ext_vector_type(8)));
typedef __bf16 bf16x4 __attribute__((ext_vector_type(4)));
typedef float f32x4 __attribute__((ext_vector_type(4)));

#define MFMA_BF16(a, b, c) __builtin_amdgcn_mfma_f32_16x16x32_bf16((a), (b), (c), 0, 0, 0)

__device__ __forceinline__ void gload16(const bf16_t* g, bf16_t* l) {
  __builtin_amdgcn_global_load_lds(
      (__attribute__((address_space(1))) void*)(g),
      (__attribute__((address_space(3))) void*)(l), 16, 0, 0);
}

// ---------------------------------------------------------------------------
// Cast x and the 4 weights f32 -> bf16.  wbf layout: [Wq | Wk | Wv | Wo]
// ---------------------------------------------------------------------------
__global__ void cast_all(const float* __restrict__ x, const float* __restrict__ wk,
                         const float* __restrict__ wq, const float* __restrict__ wv,
                         const float* __restrict__ wo, bf16_t* __restrict__ xbf,
                         bf16_t* __restrict__ wbf) {
  const size_t NX = 4194304, NW = 1048576;
  size_t i = (size_t)blockIdx.x * blockDim.x + threadIdx.x;
  const size_t total4 = (NX + 4 * NW) / 4;
  const size_t stride = (size_t)gridDim.x * blockDim.x;
  for (; i < total4; i += stride) {
    size_t f = i * 4;
    const float* src;
    bf16_t* dst;
    if (f < NX) {
      src = x + f;
      dst = xbf + f;
    } else {
      size_t g = f - NX;
      size_t wsel = g >> 20;
      size_t off = g & (NW - 1);
      dst = wbf + g;
      src = (wsel == 0) ? wq + off : (wsel == 1) ? wk + off : (wsel == 2) ? wv + off : wo + off;
    }
    float4 v = *(const float4*)src;
    bf16x4 o;
    o[0] = (bf16_t)v.x; o[1] = (bf16_t)v.y; o[2] = (bf16_t)v.z; o[3] = (bf16_t)v.w;
    *(bf16x4*)dst = o;
  }
}

// ---------------------------------------------------------------------------
// NT GEMM: C[m][n] = sum_k A[m][k] * W[n][k].  128x128 tile, BK=32, 4 waves.
// sect = blockIdx.y / blocksPerSect selects the 1024-col weight section.
// If vtb != nullptr, sect==2 (the V projection) is written TRANSPOSED to
// vtb as [bh=32][d=64][l=2048] bf16 (vectorized over 4 consecutive l).
// ---------------------------------------------------------------------------
template <typename TOUT>
__global__ __launch_bounds__(256) void gemm_nt(const bf16_t* __restrict__ A,
                                               const bf16_t* __restrict__ W,
                                               TOUT* __restrict__ C, int K, int ldc,
                                               int blocksPerSect, bf16_t* __restrict__ vtb) {
  __shared__ bf16_t As[128 * 32];
  __shared__ bf16_t Bs[128 * 32];
  const int t = threadIdx.x;
  const int l = t & 63, w = t >> 6;
  const int wm = w >> 1, wn = w & 1;
  const int lr = l & 15, lg = l >> 4;
  const int bm = blockIdx.x;
  const int by = blockIdx.y;
  const int sect = by / blocksPerSect;
  const int bn = by - sect * blocksPerSect;
  const bf16_t* Wp = W + ((size_t)sect << 20);
  const int n0 = sect * 1024 + bn * 128;

  const bf16_t* ag = A + (size_t)(bm * 128 + (t >> 2)) * K + (t & 3) * 8;
  const bf16_t* bg = Wp + (size_t)(bn * 128 + (t >> 2)) * K + (t & 3) * 8;
  const size_t rs64 = (size_t)64 * K;

  f32x4 acc[4][4];
#pragma unroll
  for (int i = 0; i < 4; ++i)
#pragma unroll
    for (int j = 0; j < 4; ++j) acc[i][j] = (f32x4){0.f, 0.f, 0.f, 0.f};

  for (int k0 = 0; k0 < K; k0 += 32) {
    __syncthreads();
    gload16(ag, As + t * 8);
    gload16(ag + rs64, As + 2048 + t * 8);
    gload16(bg, Bs + t * 8);
    gload16(bg + rs64, Bs + 2048 + t * 8);
    ag += 32;
    bg += 32;
    __syncthreads();
    bf16x8 af[4], bfr[4];
#pragma unroll
    for (int mf = 0; mf < 4; ++mf)
      af[mf] = *(const bf16x8*)(As + (wm * 64 + mf * 16 + lr) * 32 + lg * 8);
#pragma unroll
    for (int nf = 0; nf < 4; ++nf)
      bfr[nf] = *(const bf16x8*)(Bs + (wn * 64 + nf * 16 + lr) * 32 + lg * 8);
#pragma unroll
    for (int mf = 0; mf < 4; ++mf)
#pragma unroll
      for (int nf = 0; nf < 4; ++nf)
        acc[mf][nf] = MFMA_BF16(af[mf], bfr[nf], acc[mf][nf]);
  }

  if (vtb != nullptr && sect == 2) {
    // V projection: write transposed.  acc row j -> consecutive l in Vt.
#pragma unroll
    for (int mf = 0; mf < 4; ++mf)
#pragma unroll
      for (int nf = 0; nf < 4; ++nf) {
        int row0 = bm * 128 + wm * 64 + mf * 16 + lg * 4;  // l index (j adds 0..3)
        int colg = bn * 128 + wn * 64 + nf * 16 + lr;      // 0..1023 -> (h,d)
        int bb = row0 >> 11, ll = row0 & 2047;
        size_t vaddr = ((size_t)((bb * 16 + (colg >> 6)) * 64 + (colg & 63))) * 2048 + ll;
        bf16x4 pk;
#pragma unroll
        for (int j = 0; j < 4; ++j) pk[j] = (bf16_t)acc[mf][nf][j];
        *(bf16x4*)(vtb + vaddr) = pk;
      }
  } else {
#pragma unroll
    for (int mf = 0; mf < 4; ++mf)
#pragma unroll
      for (int nf = 0; nf < 4; ++nf)
#pragma unroll
        for (int j = 0; j < 4; ++j) {
          int row = bm * 128 + wm * 64 + mf * 16 + lg * 4 + j;
          int col = n0 + wn * 64 + nf * 16 + lr;
          C[(size_t)row * ldc + col] = (TOUT)acc[mf][nf][j];
        }
  }
}

// ---------------------------------------------------------------------------
// Flash attention (causal), swapped-QK^T form.
// Block = 4 waves = 64 q rows of one (b,h); wave owns 16 q rows (q = lr).
// qk:  [4096][2048] bf16, sections Q|K.   vt: [32 bh][64 d][2048 l] bf16.
// out: [4096][1024] bf16.
// K/V LDS tiles are [64][64] with 16B-chunk XOR swizzle (chunk ^= row&7),
// staged linearly by global_load_lds with the swizzle pre-applied to the
// global source address (both-sides rule).
// ---------------------------------------------------------------------------
__global__ __launch_bounds__(256) void attn_fwd(const bf16_t* __restrict__ qk,
                                                const bf16_t* __restrict__ vt,
                                                bf16_t* __restrict__ out) {
  __shared__ bf16_t Ks[64 * 64];
  __shared__ bf16_t Vts[64 * 64];   // [d][kv]
  __shared__ bf16_t Pt[4][16 * 72]; // per-wave P^T as [q=16][kv=64, pad 72]
  const int t = threadIdx.x, l = t & 63, w = t >> 6;
  const int lr = l & 15, lg = l >> 4;
  const int bh = blockIdx.x;
  const int b = bh >> 4, h = bh & 15;
  const int qt = (int)(gridDim.y - 1) - (int)blockIdx.y;  // heavy tiles first
  const int qrow = qt * 64 + w * 16 + lr;

  // Q fragment, pre-scaled by 1/sqrt(dh)=0.125 (exact in bf16)
  const bf16_t* Qg = qk + (size_t)(b * 2048 + qrow) * 2048 + h * 64 + lg * 8;
  bf16x8 qf0 = *(const bf16x8*)(Qg);
  bf16x8 qf1 = *(const bf16x8*)(Qg + 32);
#pragma unroll
  for (int j = 0; j < 8; ++j) {
    qf0[j] = (bf16_t)((float)qf0[j] * 0.125f);
    qf1[j] = (bf16_t)((float)qf1[j] * 0.125f);
  }

  f32x4 acc_o[4];
#pragma unroll
  for (int df = 0; df < 4; ++df) acc_o[df] = (f32x4){0.f, 0.f, 0.f, 0.f};
  float m_r = -1e30f, l_r = 0.f;
  bf16_t* Pw = &Pt[w][0];

  const int srow = t >> 3;  // 0..31 (staging row within half-tile)
  const int sc8 = t & 7;    // 16B chunk within 128B row

  for (int kt = 0; kt <= qt; ++kt) {
    __syncthreads();
#pragma unroll
    for (int r = 0; r < 2; ++r) {
      int row = r * 32 + srow;
      int cs = sc8 ^ (row & 7);  // pre-swizzled source chunk
      gload16(qk + (size_t)(b * 2048 + kt * 64 + row) * 2048 + 1024 + h * 64 + cs * 8,
              Ks + (r * 256 + t) * 8);
      gload16(vt + ((size_t)(bh * 64 + row)) * 2048 + kt * 64 + cs * 8,
              Vts + (r * 256 + t) * 8);
    }
    __syncthreads();

    // --- S^T = K (Q/8)^T : rows = kv, cols = q(=lr) ---
    f32x4 sc[4];
#pragma unroll
    for (int nf = 0; nf < 4; ++nf) sc[nf] = (f32x4){0.f, 0.f, 0.f, 0.f};
#pragma unroll
    for (int nf = 0; nf < 4; ++nf) {
      int row = nf * 16 + lr;
      int r7 = row & 7;
      bf16x8 kf0 = *(const bf16x8*)(Ks + row * 64 + ((lg ^ r7) * 8));
      bf16x8 kf1 = *(const bf16x8*)(Ks + row * 64 + (((lg ^ 4) ^ r7) * 8));
      sc[nf] = MFMA_BF16(kf0, qf0, sc[nf]);
      sc[nf] = MFMA_BF16(kf1, qf1, sc[nf]);
    }
    float s[16];
#pragma unroll
    for (int nf = 0; nf < 4; ++nf)
#pragma unroll
      for (int j = 0; j < 4; ++j) s[nf * 4 + j] = sc[nf][j];
    if (kt == qt) {
      const int qloc = w * 16 + lr;
#pragma unroll
      for (int nf = 0; nf < 4; ++nf)
#pragma unroll
        for (int j = 0; j < 4; ++j)
          if (nf * 16 + lg * 4 + j > qloc) s[nf * 4 + j] = -1e30f;
    }

    // --- online softmax: lane owns one q row; 15 in-reg max + 2 shfls ---
    float m16 = s[0];
#pragma unroll
    for (int i = 1; i < 16; ++i) m16 = fmaxf(m16, s[i]);
    float rm = fmaxf(m16, __shfl_xor(m16, 16));
    rm = fmaxf(rm, __shfl_xor(rm, 32));
    float mnew = fmaxf(m_r, rm);
    float sf = __expf(m_r - mnew);
    m_r = mnew;
    float p[16], ps = 0.f;
#pragma unroll
    for (int i = 0; i < 16; ++i) {
      p[i] = __expf(s[i] - mnew);
      ps += p[i];
    }
    ps += __shfl_xor(ps, 16);
    ps += __shfl_xor(ps, 32);
    l_r = l_r * sf + ps;
#pragma unroll
    for (int df = 0; df < 4; ++df)
#pragma unroll
      for (int j = 0; j < 4; ++j) acc_o[df][j] *= sf;

    // --- P^T -> LDS (vectorized bf16x4 writes) ---
#pragma unroll
    for (int nf = 0; nf < 4; ++nf) {
      bf16x4 pk;
#pragma unroll
      for (int j = 0; j < 4; ++j) pk[j] = (bf16_t)p[nf * 4 + j];
      *(bf16x4*)(Pw + lr * 72 + nf * 16 + lg * 4) = pk;
    }

    // --- O^T += Vt P^T ---
    bf16x8 pb0 = *(const bf16x8*)(Pw + lr * 72 + lg * 8);
    bf16x8 pb1 = *(const bf16x8*)(Pw + lr * 72 + 32 + lg * 8);
#pragma unroll
    for (int df = 0; df < 4; ++df) {
      int arow = df * 16 + lr;
      int r7 = arow & 7;
      bf16x8 vf0 = *(const bf16x8*)(Vts + arow * 64 + ((lg ^ r7) * 8));
      bf16x8 vf1 = *(const bf16x8*)(Vts + arow * 64 + (((lg ^ 4) ^ r7) * 8));
      acc_o[df] = MFMA_BF16(vf0, pb0, acc_o[df]);
      acc_o[df] = MFMA_BF16(vf1, pb1, acc_o[df]);
    }
  }

  // --- normalize + write (lane owns q row; d contiguous over j) ---
  float inv = 1.f / l_r;
#pragma unroll
  for (int df = 0; df < 4; ++df) {
    bf16x4 o;
#pragma unroll
    for (int j = 0; j < 4; ++j) o[j] = (bf16_t)(acc_o[df][j] * inv);
    *(bf16x4*)(out + (size_t)(b * 2048 + qrow) * 1024 + h * 64 + df * 16 + lg * 4) = o;
  }
}

// ---------------------------------------------------------------------------
extern "C" void kernel_launch(void* const* d_in, const int* in_sizes, int n_in,
                              void* d_out, int out_size, void* d_ws, size_t ws_size,
                              hipStream_t stream) {
  const float* x = (const float*)d_in[0];
  const float* wk = (const float*)d_in[1];
  const float* wq = (const float*)d_in[2];
  const float* wv = (const float*)d_in[3];
  const float* wo = (const float*)d_in[4];

  bf16_t* xbf = (bf16_t*)d_ws;           // 4 Mi elems (8 MB)
  bf16_t* wbf = xbf + 4194304;           // 4 Mi elems (8 MB): [Wq|Wk|Wv|Wo]
  bf16_t* qkbf = wbf + 4194304;          // 8 Mi elems (16 MB): [Q|K] cols
  bf16_t* vtbuf = qkbf + 8388608;        // 4 Mi elems (8 MB): V transposed
  bf16_t* attnbf = xbf;                  // alias: xbf dead after QKV gemm
  float* out = (float*)d_out;

  cast_all<<<dim3(2048), dim3(256), 0, stream>>>(x, wk, wq, wv, wo, xbf, wbf);
  gemm_nt<bf16_t><<<dim3(32, 24), dim3(256), 0, stream>>>(xbf, wbf, qkbf, 1024, 2048, 8, vtbuf);
  attn_fwd<<<dim3(32, 32), dim3(256), 0, stream>>>(qkbf, vtbuf, attnbf);
  gemm_nt<float><<<dim3(32, 8), dim3(256), 0, stream>>>(attnbf, wbf + 3 * 1048576, out, 1024,
                                                        1024, 8, (bf16_t*)nullptr);
}